// Round 2
// baseline (304.319 us; speedup 1.0000x reference)
//
#include <hip/hip_runtime.h>

// Problem constants (from reference): B,T,V,C,K = 256,2048,128,512,10
#define B_ 256
#define T_ 2048
#define V_ 128
#define C_ 512
#define K_ 10

// d_out layout: w (B*V) | kappa (B*K) | phi (B*T), all fp32
#define W_OFF 0
#define KAPPA_OFF (B_ * V_)            // 32768
#define PHI_OFF   (B_ * V_ + B_ * K_)  // 35328

// Row-skip threshold. A row can have phi >= EPS only if at least one of the
// K=10 components alpha_k*exp(-beta_k d^2) >= EPS/10 = TAU. The test
// d^2 * beta_k <= L_k with L_k = ln(alpha_k/TAU) is exactly the analytic
// interval |t - kappa_k| <= sqrt(L_k/beta_k); since alpha_k = exp(acc+bias),
// L_k = acc + bias + ln(1e8) — computed with NO log. Skipped rows contribute
// < EPS each (worst-case total 2048*EPS = 2e-4, far below the 4e-2 pass
// threshold). Same bound applies to storing phi=0 for inactive rows.
#define EPS 1e-7f
#define LN_INV_TAU 18.420681f  // ln(1e8) = ln(K/EPS)

#define NG 32           // 32 groups of 32 lanes (1024 threads)
#define RPG (T_ / NG)   // 64 candidate rows per group

typedef float f4_t __attribute__((ext_vector_type(4)));

// One block per batch row b (grid 256 x 1024 threads, 1 block/CU):
//  1. Params GEMM with NO pre-barrier: each of the 30 dot-groups loads its
//     W row AND the x row directly from global (x addresses identical
//     across groups -> one HBM fetch, L1 broadcast). Width-32 shuffle
//     reduce; exp -> alpha/beta/kappa (+ L_k = acc+bias+ln(1e8)); barrier.
//  2. Barrier-free activity tests d^2*beta_k <= L_k for both the group-row
//     mapping (mask) and the phi mapping; ballot -> 64-bit row mask; issue
//     4-deep onehot load pipeline IMMEDIATELY.
//  3. phi: active threads do the 10-exp sum; inactive store 0 (execz skips
//     whole waves). Nontemporal store + LDS stage; barrier.
//  4. Drain pipeline (coalesced 512 B rows, nontemporal), LDS-reduce 32
//     group partials, write w. Single dispatch: no memset, no atomics.
__global__ __launch_bounds__(1024) void window_fused(
    const float* __restrict__ x, const float* __restrict__ kappa_old,
    const float* __restrict__ W, const float* __restrict__ bias,
    const float* __restrict__ onehots, float* __restrict__ out) {
  const int b = blockIdx.x;
  const int tid = threadIdx.x;
  const int j = tid >> 5;  // group / dot index (0..31)
  const int l = tid & 31;  // lane within 32-lane group

  __shared__ float alpha_s[K_];
  __shared__ float beta_s[K_];
  __shared__ float kap_s[K_];
  __shared__ float L_s[K_];
  __shared__ float phs[T_];      // 8 KB
  __shared__ float red[NG * V_]; // 16 KB

  // --- phase 1: params GEMM, no staging barrier ---
  if (j < 3 * K_) {
    const f4_t* Wr = (const f4_t*)(W + j * C_);
    const f4_t* xr = (const f4_t*)(x + b * C_);
    f4_t w4[4], x4[4];
#pragma unroll
    for (int m = 0; m < 4; ++m) {
      w4[m] = Wr[m * 32 + l];
      x4[m] = xr[m * 32 + l];
    }
    // same-address broadcast loads (issue early, overlap W/x latency)
    const float bj = bias[j];
    const float ko = (j >= 2 * K_) ? kappa_old[b * K_ + (j - 2 * K_)] : 0.0f;

    f4_t a4 = {0.f, 0.f, 0.f, 0.f};
#pragma unroll
    for (int m = 0; m < 4; ++m) a4 += w4[m] * x4[m];
    float acc = (a4.x + a4.y) + (a4.z + a4.w);
    acc += __shfl_down(acc, 16, 32);
    acc += __shfl_down(acc, 8, 32);
    acc += __shfl_down(acc, 4, 32);
    acc += __shfl_down(acc, 2, 32);
    acc += __shfl_down(acc, 1, 32);
    if (l == 0) {
      const float s = acc + bj;
      const float p = __expf(s);
      if (j < K_) {
        alpha_s[j] = p;
        L_s[j] = s + LN_INV_TAU;  // ln(alpha_k/TAU), no log needed
      } else if (j < 2 * K_) {
        beta_s[j - K_] = p;
      } else {
        const int k = j - 2 * K_;
        const float kk = ko + p;
        kap_s[k] = kk;
        out[KAPPA_OFF + b * K_ + k] = kk;
      }
    }
  }
  __syncthreads();

  // --- phase 2: barrier-free activity tests ---
  // mask mapping: group g owns rows t = g + 32*jj (lane l tests jj=l, l+32)
  // phi  mapping: thread tid owns t = tid and tid + 1024
  const float tm0 = (float)(j + 32 * l);
  const float tp0 = (float)tid;
  bool am0 = false, am1 = false, ap0 = false, ap1 = false;
#pragma unroll
  for (int k = 0; k < K_; ++k) {
    const float ka = kap_s[k], be = beta_s[k], Lk = L_s[k];
    float d;
    d = tm0 - ka;           am0 |= (d * d * be <= Lk);
    d = tm0 + 1024.f - ka;  am1 |= (d * d * be <= Lk);
    d = tp0 - ka;           ap0 |= (d * d * be <= Lk);
    d = tp0 + 1024.f - ka;  ap1 |= (d * d * be <= Lk);
  }
  const unsigned long long ba0 = __ballot(am0);
  const unsigned long long ba1 = __ballot(am1);
  const unsigned int m0 =
      (j & 1) ? (unsigned int)(ba0 >> 32) : (unsigned int)ba0;
  const unsigned int m1 =
      (j & 1) ? (unsigned int)(ba1 >> 32) : (unsigned int)ba1;
  unsigned long long mask =
      (unsigned long long)m0 | ((unsigned long long)m1 << 32);

  const f4_t* p0 =
      (const f4_t*)(onehots + ((size_t)b * T_ + j) * V_) + l;
  // row jj at p0 + jj*1024 (f4 units) = jj * 16 KB

  f4_t acc4 = {0.f, 0.f, 0.f, 0.f};
  int j0 = -1, j1 = -1, j2 = -1, j3 = -1;
  f4_t o0 = acc4, o1 = acc4, o2 = acc4, o3 = acc4;
  if (mask) { j0 = __builtin_ctzll(mask); mask &= mask - 1;
              o0 = __builtin_nontemporal_load(p0 + (size_t)j0 * 1024); }
  if (mask) { j1 = __builtin_ctzll(mask); mask &= mask - 1;
              o1 = __builtin_nontemporal_load(p0 + (size_t)j1 * 1024); }
  if (mask) { j2 = __builtin_ctzll(mask); mask &= mask - 1;
              o2 = __builtin_nontemporal_load(p0 + (size_t)j2 * 1024); }
  if (mask) { j3 = __builtin_ctzll(mask); mask &= mask - 1;
              o3 = __builtin_nontemporal_load(p0 + (size_t)j3 * 1024); }

  // --- phase 3: phi (active threads only); overlaps in-flight loads ---
#pragma unroll
  for (int half = 0; half < 2; ++half) {
    const int t = tid + half * 1024;
    const bool active = half ? ap1 : ap0;
    float ph = 0.0f;
    if (active) {
      const float ft = (float)t;
#pragma unroll
      for (int k = 0; k < K_; k++) {
        const float d = kap_s[k] - ft;
        ph += alpha_s[k] * __expf(-beta_s[k] * d * d);
      }
    }
    phs[t] = ph;
    __builtin_nontemporal_store(ph, out + PHI_OFF + b * T_ + t);
  }
  __syncthreads();

  // --- phase 4: drain pipeline, weighting by actual phi ---
  while (j0 >= 0) {
    acc4 += phs[j + 32 * j0] * o0;
    j0 = j1; o0 = o1;
    j1 = j2; o1 = o2;
    j2 = j3; o2 = o3;
    if (mask) { j3 = __builtin_ctzll(mask); mask &= mask - 1;
                o3 = __builtin_nontemporal_load(p0 + (size_t)j3 * 1024); }
    else j3 = -1;
  }

  *(f4_t*)&red[j * V_ + l * 4] = acc4;
  __syncthreads();

  // --- final reduce: 128 threads sum 32 partials each, write w directly ---
  if (tid < V_) {
    float s0 = 0.0f;
#pragma unroll
    for (int r = 0; r < NG; r++) s0 += red[r * V_ + tid];
    out[W_OFF + b * V_ + tid] = s0;
  }
}

extern "C" void kernel_launch(void* const* d_in, const int* in_sizes, int n_in,
                              void* d_out, int out_size, void* d_ws,
                              size_t ws_size, hipStream_t stream) {
  const float* x         = (const float*)d_in[0];  // (B, C)
  const float* kappa_old = (const float*)d_in[1];  // (B, K)
  const float* onehots   = (const float*)d_in[2];  // (B, T, V)
  const float* W         = (const float*)d_in[3];  // (3K, C)
  const float* bias      = (const float*)d_in[4];  // (3K,)
  float* out = (float*)d_out;                      // w | kappa | phi

  window_fused<<<dim3(B_), dim3(1024), 0, stream>>>(x, kappa_old, W, bias,
                                                    onehots, out);
}